// Round 1
// baseline (611.990 us; speedup 1.0000x reference)
//
#include <hip/hip_runtime.h>
#include <hip/hip_bf16.h>
#include <math.h>

// Problem constants
#define NRES 512
#define CS 384
#define CZ 128
#define NH 12
#define CC 16
#define NQP 4
#define NPV 8
#define HC (NH*CC)        // 192
#define W_C 0.23570226039551584f   // sqrt(2/(9*4))
#define W_L 0.5773502691896258f    // sqrt(1/3)

// ---------------- Kernel 1: projections + warp + qn/kn ----------------
__global__ __launch_bounds__(256) void k_proj(
    const float* __restrict__ s, const float* __restrict__ T,
    const float* __restrict__ Wq, const float* __restrict__ bq,
    const float* __restrict__ Wk, const float* __restrict__ bk,
    const float* __restrict__ Wv, const float* __restrict__ bv,
    const float* __restrict__ Wqp, const float* __restrict__ bqp,
    const float* __restrict__ Wkp, const float* __restrict__ bkp,
    const float* __restrict__ Wvp, const float* __restrict__ bvp,
    float* __restrict__ q_s, float* __restrict__ k_, float* __restrict__ v_,
    float* __restrict__ wq, float* __restrict__ wk, float* __restrict__ wv,
    float* __restrict__ qn, float* __restrict__ kn)
{
    int n = blockIdx.x;
    int tid = threadIdx.x;
    __shared__ float sl[CS];
    __shared__ float Rl[9];
    __shared__ float tl[3];
    __shared__ float rawq[144], rawk[144], rawv[288];
    __shared__ float sq_part[48], sk_part[48];

    for (int i = tid; i < CS; i += 256) sl[i] = s[n*CS + i];
    if (tid < 9)  Rl[tid] = T[n*16 + (tid/3)*4 + (tid%3)];
    if (tid >= 16 && tid < 19) tl[tid-16] = T[n*16 + (tid-16)*4 + 3];
    __syncthreads();

    // q, k, v projections (fout = 192 each)
    for (int f = tid; f < HC; f += 256) {
        float aq = bq[f], ak = bk[f], av = bv[f];
        #pragma unroll 4
        for (int i = 0; i < CS; ++i) {
            float sv = sl[i];
            aq += sv * Wq[i*HC + f];
            ak += sv * Wk[i*HC + f];
            av += sv * Wv[i*HC + f];
        }
        int h = f >> 4, c = f & 15;
        q_s[((size_t)h*NRES + n)*CC + c] = aq * 0.25f;  // pre-scale 1/sqrt(C)
        k_ [((size_t)h*NRES + n)*CC + c] = ak;
        v_ [((size_t)h*NRES + n)*CC + c] = av;
    }
    // qp, kp raw projections (144 each: idx = x*48 + h*4 + p)
    for (int f = tid; f < 144; f += 256) {
        float a = bqp[f], b2 = bkp[f];
        #pragma unroll 4
        for (int i = 0; i < CS; ++i) {
            float sv = sl[i];
            a  += sv * Wqp[i*144 + f];
            b2 += sv * Wkp[i*144 + f];
        }
        rawq[f] = a; rawk[f] = b2;
    }
    // vp raw (288: idx = x*96 + h*8 + p)
    for (int f = tid; f < 288; f += 256) {
        float a = bvp[f];
        #pragma unroll 4
        for (int i = 0; i < CS; ++i) a += sl[i] * Wvp[i*288 + f];
        rawv[f] = a;
    }
    __syncthreads();

    // warp qp/kp: 48 (h,p) pairs
    if (tid < 48) {
        int h = tid >> 2, p = tid & 3;
        float qy0 = rawq[0*48 + h*4 + p], qy1 = rawq[1*48 + h*4 + p], qy2 = rawq[2*48 + h*4 + p];
        float ky0 = rawk[0*48 + h*4 + p], ky1 = rawk[1*48 + h*4 + p], ky2 = rawk[2*48 + h*4 + p];
        float qs2 = 0.f, ks2 = 0.f;
        #pragma unroll
        for (int x = 0; x < 3; ++x) {
            float wqv = Rl[x*3+0]*qy0 + Rl[x*3+1]*qy1 + Rl[x*3+2]*qy2 + tl[x];
            float wkv = Rl[x*3+0]*ky0 + Rl[x*3+1]*ky1 + Rl[x*3+2]*ky2 + tl[x];
            wq[((size_t)h*NRES + n)*12 + p*3 + x] = wqv;
            wk[((size_t)h*NRES + n)*12 + p*3 + x] = wkv;
            qs2 += wqv*wqv; ks2 += wkv*wkv;
        }
        sq_part[tid] = qs2; sk_part[tid] = ks2;
    } else if (tid >= 64 && tid < 160) {
        int u = tid - 64; int h = u >> 3, p = u & 7;
        float y0 = rawv[0*96 + h*8 + p], y1 = rawv[1*96 + h*8 + p], y2 = rawv[2*96 + h*8 + p];
        #pragma unroll
        for (int x = 0; x < 3; ++x) {
            wv[((size_t)h*NRES + n)*24 + p*3 + x] =
                Rl[x*3+0]*y0 + Rl[x*3+1]*y1 + Rl[x*3+2]*y2 + tl[x];
        }
    }
    __syncthreads();
    if (tid < NH) {
        float a = sq_part[tid*4] + sq_part[tid*4+1] + sq_part[tid*4+2] + sq_part[tid*4+3];
        float b2 = sk_part[tid*4] + sk_part[tid*4+1] + sk_part[tid*4+2] + sk_part[tid*4+3];
        qn[(size_t)tid*NRES + n] = a;
        kn[(size_t)tid*NRES + n] = b2;
    }
}

// ---------------- Kernel 2: bias = z @ Wb + bb  -> [H][N][N] ----------------
__global__ __launch_bounds__(384) void k_bias(
    const float* __restrict__ z, const float* __restrict__ Wb,
    const float* __restrict__ bb, float* __restrict__ bias)
{
    __shared__ float zl[32*129];
    __shared__ float wbl[128*12];
    __shared__ float bbl[12];
    int i = blockIdx.y, j0 = blockIdx.x * 32;
    int tid = threadIdx.x;
    for (int idx = tid; idx < 128*12; idx += 384) wbl[idx] = Wb[idx];
    if (tid < 12) bbl[tid] = bb[tid];
    for (int idx = tid; idx < 32*128; idx += 384) {
        int j = idx >> 7, c = idx & 127;
        zl[j*129 + c] = z[((size_t)i*NRES + j0 + j)*CZ + c];
    }
    __syncthreads();
    int h = tid / 32, j = tid % 32;
    float acc = bbl[h];
    #pragma unroll 8
    for (int c = 0; c < 128; ++c) acc += zl[j*129 + c] * wbl[c*12 + h];
    bias[((size_t)h*NRES + i)*NRES + j0 + j] = acc;
}

// ------- Kernel 3: attention row softmax (in-place att over bias) + v_out/o_pt -------
__global__ __launch_bounds__(256) void k_att(
    const float* __restrict__ q_s, const float* __restrict__ k_,
    const float* __restrict__ wq, const float* __restrict__ wk,
    const float* __restrict__ qn, const float* __restrict__ kn,
    const float* __restrict__ hw,
    float* __restrict__ bias,       // in: bias, out: att
    const float* __restrict__ v_, const float* __restrict__ wv,
    float* __restrict__ vout, float* __restrict__ opt)
{
    int i = blockIdx.x, h = blockIdx.y;
    int tid = threadIdx.x;
    __shared__ float ql[16], wql[12];
    __shared__ float att[NRES];
    __shared__ float red[256];
    __shared__ float sQn, sG, sMax, sInv;

    if (tid < 16) ql[tid] = q_s[((size_t)h*NRES + i)*CC + tid];
    else if (tid < 28) wql[tid-16] = wq[((size_t)h*NRES + i)*12 + (tid-16)];
    if (tid == 0) {
        sQn = qn[(size_t)h*NRES + i];
        float x = hw[h];
        float sp = (x > 20.f) ? x : log1pf(expf(x));
        sG = sp * W_C * 0.5f;
    }
    __syncthreads();

    float lg[2];
    #pragma unroll
    for (int m = 0; m < 2; ++m) {
        int j = tid + m*256;
        const float* kp  = &k_[((size_t)h*NRES + j)*CC];
        const float* wkp = &wk[((size_t)h*NRES + j)*12];
        float qk = 0.f;
        #pragma unroll
        for (int c = 0; c < 16; ++c) qk += ql[c]*kp[c];
        float dd = 0.f;
        #pragma unroll
        for (int c = 0; c < 12; ++c) dd += wql[c]*wkp[c];
        float d2 = sQn + kn[(size_t)h*NRES + j] - 2.f*dd;
        lg[m] = W_L * (qk + bias[((size_t)h*NRES + i)*NRES + j] - sG*d2);
    }
    // block max
    red[tid] = fmaxf(lg[0], lg[1]);
    __syncthreads();
    for (int s2 = 128; s2 > 0; s2 >>= 1) {
        if (tid < s2) red[tid] = fmaxf(red[tid], red[tid+s2]);
        __syncthreads();
    }
    if (tid == 0) sMax = red[0];
    __syncthreads();
    float mx = sMax;
    float e0 = __expf(lg[0]-mx), e1 = __expf(lg[1]-mx);
    red[tid] = e0 + e1;
    __syncthreads();
    for (int s2 = 128; s2 > 0; s2 >>= 1) {
        if (tid < s2) red[tid] += red[tid+s2];
        __syncthreads();
    }
    if (tid == 0) sInv = 1.f / red[0];
    __syncthreads();
    float inv = sInv;
    float a0 = e0*inv, a1 = e1*inv;
    att[tid] = a0; att[tid+256] = a1;
    bias[((size_t)h*NRES + i)*NRES + tid]       = a0;
    bias[((size_t)h*NRES + i)*NRES + tid + 256] = a1;
    __syncthreads();

    // v_out (16) and o_pt (24): 40 length-512 reductions, one per wave-round
    int wave = tid >> 6, lane = tid & 63;
    for (int oi = wave; oi < 40; oi += 4) {
        float part = 0.f;
        if (oi < 16) {
            #pragma unroll
            for (int jj = 0; jj < 8; ++jj) {
                int j = lane + jj*64;
                part += att[j] * v_[((size_t)h*NRES + j)*CC + oi];
            }
        } else {
            int e = oi - 16;
            #pragma unroll
            for (int jj = 0; jj < 8; ++jj) {
                int j = lane + jj*64;
                part += att[j] * wv[((size_t)h*NRES + j)*24 + e];
            }
        }
        #pragma unroll
        for (int d = 32; d > 0; d >>= 1) part += __shfl_down(part, d);
        if (lane == 0) {
            if (oi < 16) vout[(size_t)i*HC + h*CC + oi] = part;
            else         opt [(size_t)i*288 + h*24 + (oi-16)] = part;
        }
    }
}

// ---------------- Kernel 4: pairwise_out = att @ z  per i ----------------
__global__ __launch_bounds__(256) void k_pair(
    const float* __restrict__ z, const float* __restrict__ att,
    float* __restrict__ pout)
{
    int i = blockIdx.x, tid = threadIdx.x;
    __shared__ float zl[64*129];
    __shared__ float al[12*64];
    int c = tid & 127, hh = tid >> 7;  // hh in {0,1}
    float acc[6] = {0,0,0,0,0,0};
    for (int j0 = 0; j0 < NRES; j0 += 64) {
        __syncthreads();
        for (int idx = tid; idx < 64*128; idx += 256) {
            int j = idx >> 7, cc = idx & 127;
            zl[j*129 + cc] = z[((size_t)i*NRES + j0 + j)*CZ + cc];
        }
        for (int idx = tid; idx < 12*64; idx += 256) {
            int h2 = idx >> 6, jj = idx & 63;
            al[h2*64 + jj] = att[((size_t)h2*NRES + i)*NRES + j0 + jj];
        }
        __syncthreads();
        for (int jj = 0; jj < 64; ++jj) {
            float zv = zl[jj*129 + c];
            #pragma unroll
            for (int m = 0; m < 6; ++m) {
                acc[m] += al[(hh + 2*m)*64 + jj] * zv;
            }
        }
    }
    #pragma unroll
    for (int m = 0; m < 6; ++m) {
        pout[(size_t)i*1536 + (hh + 2*m)*128 + c] = acc[m];
    }
}

// ---------------- Kernel 5: assemble cat and final projection ----------------
__global__ __launch_bounds__(384) void k_final(
    const float* __restrict__ vout, const float* __restrict__ opt,
    const float* __restrict__ pout, const float* __restrict__ T,
    const float* __restrict__ Wo, const float* __restrict__ bo,
    float* __restrict__ out)
{
    int i0 = blockIdx.x * 4, tid = threadIdx.x;
    __shared__ float cat[4][2112];
    for (int m = 0; m < 4; ++m) {
        int i = i0 + m;
        for (int f = tid; f < 192; f += 384)  cat[m][f] = vout[(size_t)i*HC + f];
        for (int f = tid; f < 1536; f += 384) cat[m][576 + f] = pout[(size_t)i*1536 + f];
        if (tid < 96) {
            int h = tid >> 3, p = tid & 7;
            float y0 = opt[(size_t)i*288 + h*24 + p*3 + 0] - T[i*16 + 0*4 + 3];
            float y1 = opt[(size_t)i*288 + h*24 + p*3 + 1] - T[i*16 + 1*4 + 3];
            float y2 = opt[(size_t)i*288 + h*24 + p*3 + 2] - T[i*16 + 2*4 + 3];
            float n2 = 0.f;
            #pragma unroll
            for (int x = 0; x < 3; ++x) {
                // o_local_x = sum_y R[y][x] * y_y   (R^T)
                float w = T[i*16 + 0*4 + x]*y0 + T[i*16 + 1*4 + x]*y1 + T[i*16 + 2*4 + x]*y2;
                cat[m][192 + x*96 + h*8 + p] = w;
                n2 += w*w;
            }
            cat[m][480 + h*8 + p] = sqrtf(n2);
        }
    }
    __syncthreads();
    int o = tid;
    float acc0 = bo[o], acc1 = bo[o], acc2 = bo[o], acc3 = bo[o];
    for (int f = 0; f < 2112; ++f) {
        float w = Wo[(size_t)f*CS + o];
        acc0 += cat[0][f]*w;
        acc1 += cat[1][f]*w;
        acc2 += cat[2][f]*w;
        acc3 += cat[3][f]*w;
    }
    out[(size_t)(i0+0)*CS + o] = acc0;
    out[(size_t)(i0+1)*CS + o] = acc1;
    out[(size_t)(i0+2)*CS + o] = acc2;
    out[(size_t)(i0+3)*CS + o] = acc3;
}

// ---------------- launch ----------------
extern "C" void kernel_launch(void* const* d_in, const int* in_sizes, int n_in,
                              void* d_out, int out_size, void* d_ws, size_t ws_size,
                              hipStream_t stream)
{
    const float* s   = (const float*)d_in[0];
    const float* z   = (const float*)d_in[1];
    const float* T   = (const float*)d_in[2];
    const float* Wq  = (const float*)d_in[3];  const float* bq  = (const float*)d_in[4];
    const float* Wk  = (const float*)d_in[5];  const float* bk  = (const float*)d_in[6];
    const float* Wv  = (const float*)d_in[7];  const float* bv  = (const float*)d_in[8];
    const float* Wqp = (const float*)d_in[9];  const float* bqp = (const float*)d_in[10];
    const float* Wkp = (const float*)d_in[11]; const float* bkp = (const float*)d_in[12];
    const float* Wvp = (const float*)d_in[13]; const float* bvp = (const float*)d_in[14];
    const float* Wb  = (const float*)d_in[15]; const float* bb  = (const float*)d_in[16];
    const float* Wo  = (const float*)d_in[17]; const float* bo  = (const float*)d_in[18];
    const float* hw  = (const float*)d_in[19];
    float* out = (float*)d_out;
    float* ws  = (float*)d_ws;

    // workspace layout (floats)
    size_t off = 0;
    float* q_s  = ws + off; off += (size_t)NH*NRES*CC;      // 98304
    float* k_   = ws + off; off += (size_t)NH*NRES*CC;
    float* v_   = ws + off; off += (size_t)NH*NRES*CC;
    float* wq   = ws + off; off += (size_t)NH*NRES*12;      // 73728
    float* wk   = ws + off; off += (size_t)NH*NRES*12;
    float* wv   = ws + off; off += (size_t)NH*NRES*24;      // 147456
    float* qn   = ws + off; off += (size_t)NH*NRES;
    float* kn   = ws + off; off += (size_t)NH*NRES;
    float* bias = ws + off; off += (size_t)NH*NRES*NRES;    // 3.1M (also att, in-place)
    float* vout = ws + off; off += (size_t)NRES*HC;
    float* opt  = ws + off; off += (size_t)NRES*288;
    float* pout = ws + off; off += (size_t)NRES*1536;

    k_proj<<<dim3(NRES), dim3(256), 0, stream>>>(
        s, T, Wq, bq, Wk, bk, Wv, bv, Wqp, bqp, Wkp, bkp, Wvp, bvp,
        q_s, k_, v_, wq, wk, wv, qn, kn);

    k_bias<<<dim3(16, NRES), dim3(384), 0, stream>>>(z, Wb, bb, bias);

    k_att<<<dim3(NRES, NH), dim3(256), 0, stream>>>(
        q_s, k_, wq, wk, qn, kn, hw, bias, v_, wv, vout, opt);

    k_pair<<<dim3(NRES), dim3(256), 0, stream>>>(z, bias, pout);

    k_final<<<dim3(NRES/4), dim3(384), 0, stream>>>(vout, opt, pout, T, Wo, bo, out);
}

// Round 2
// 356.300 us; speedup vs baseline: 1.7176x; 1.7176x over previous
//
#include <hip/hip_runtime.h>
#include <hip/hip_bf16.h>
#include <math.h>

// Problem constants
#define NRES 512
#define CS 384
#define CZ 128
#define NH 12
#define CC 16
#define NQP 4
#define NPV 8
#define HC (NH*CC)        // 192
#define W_C 0.23570226039551584f   // sqrt(2/(9*4))
#define W_L 0.5773502691896258f    // sqrt(1/3)

// ---------------- Kernel 1: projections + warp + qn/kn ----------------
// Outputs (transposed float4-row layouts for coalesced k_att):
//   q_s  [h][n][16]            (row, float4-aligned)
//   k_t4 [(h*4+c4)*512 + n]    float4 (c = c4*4..c4*4+3)
//   v_t4 [(h*4+c4)*512 + n]    float4
//   wq   [h][n][12]            (row)
//   wk_t4[(h*3+e4)*512 + n]    float4 (e = p*3+x, e4 = e/4)
//   wv_t4[(h*6+e4)*512 + n]    float4
//   qn/kn[h][n]
__global__ __launch_bounds__(256) void k_proj(
    const float* __restrict__ s, const float* __restrict__ T,
    const float* __restrict__ Wq, const float* __restrict__ bq,
    const float* __restrict__ Wk, const float* __restrict__ bk,
    const float* __restrict__ Wv, const float* __restrict__ bv,
    const float* __restrict__ Wqp, const float* __restrict__ bqp,
    const float* __restrict__ Wkp, const float* __restrict__ bkp,
    const float* __restrict__ Wvp, const float* __restrict__ bvp,
    float* __restrict__ q_s, float4* __restrict__ k_t4, float4* __restrict__ v_t4,
    float* __restrict__ wq, float4* __restrict__ wk_t4, float4* __restrict__ wv_t4,
    float* __restrict__ qn, float* __restrict__ kn)
{
    int n = blockIdx.x;
    int tid = threadIdx.x;
    __shared__ float sl[CS];
    __shared__ float Rl[9];
    __shared__ float tl[3];
    __shared__ float rawq[144], rawk[144], rawv[288];
    __shared__ float ql_[192], kl_[192], vl_[192];
    __shared__ float wq_l[144], wk_l[144], wv_l[288];
    __shared__ float sq_part[48], sk_part[48];

    for (int i = tid; i < CS; i += 256) sl[i] = s[n*CS + i];
    if (tid < 9)  Rl[tid] = T[n*16 + (tid/3)*4 + (tid%3)];
    if (tid >= 16 && tid < 19) tl[tid-16] = T[n*16 + (tid-16)*4 + 3];
    __syncthreads();

    // q, k, v projections (fout = 192 each)
    for (int f = tid; f < HC; f += 256) {
        float aq = bq[f], ak = bk[f], av = bv[f];
        #pragma unroll 4
        for (int i = 0; i < CS; ++i) {
            float sv = sl[i];
            aq += sv * Wq[i*HC + f];
            ak += sv * Wk[i*HC + f];
            av += sv * Wv[i*HC + f];
        }
        ql_[f] = aq * 0.25f;  // pre-scale 1/sqrt(C)
        kl_[f] = ak;
        vl_[f] = av;
    }
    // qp, kp raw projections (144 each: idx = x*48 + h*4 + p)
    for (int f = tid; f < 144; f += 256) {
        float a = bqp[f], b2 = bkp[f];
        #pragma unroll 4
        for (int i = 0; i < CS; ++i) {
            float sv = sl[i];
            a  += sv * Wqp[i*144 + f];
            b2 += sv * Wkp[i*144 + f];
        }
        rawq[f] = a; rawk[f] = b2;
    }
    // vp raw (288: idx = x*96 + h*8 + p)
    for (int f = tid; f < 288; f += 256) {
        float a = bvp[f];
        #pragma unroll 4
        for (int i = 0; i < CS; ++i) a += sl[i] * Wvp[i*288 + f];
        rawv[f] = a;
    }
    __syncthreads();

    // warp qp/kp: 48 (h,p) pairs -> wq_l/wk_l (e = p*3+x); vp -> wv_l
    if (tid < 48) {
        int h = tid >> 2, p = tid & 3;
        float qy0 = rawq[0*48 + h*4 + p], qy1 = rawq[1*48 + h*4 + p], qy2 = rawq[2*48 + h*4 + p];
        float ky0 = rawk[0*48 + h*4 + p], ky1 = rawk[1*48 + h*4 + p], ky2 = rawk[2*48 + h*4 + p];
        float qs2 = 0.f, ks2 = 0.f;
        #pragma unroll
        for (int x = 0; x < 3; ++x) {
            float wqv = Rl[x*3+0]*qy0 + Rl[x*3+1]*qy1 + Rl[x*3+2]*qy2 + tl[x];
            float wkv = Rl[x*3+0]*ky0 + Rl[x*3+1]*ky1 + Rl[x*3+2]*ky2 + tl[x];
            wq_l[h*12 + p*3 + x] = wqv;
            wk_l[h*12 + p*3 + x] = wkv;
            qs2 += wqv*wqv; ks2 += wkv*wkv;
        }
        sq_part[tid] = qs2; sk_part[tid] = ks2;
    } else if (tid >= 64 && tid < 160) {
        int u = tid - 64; int h = u >> 3, p = u & 7;
        float y0 = rawv[0*96 + h*8 + p], y1 = rawv[1*96 + h*8 + p], y2 = rawv[2*96 + h*8 + p];
        #pragma unroll
        for (int x = 0; x < 3; ++x) {
            wv_l[h*24 + p*3 + x] = Rl[x*3+0]*y0 + Rl[x*3+1]*y1 + Rl[x*3+2]*y2 + tl[x];
        }
    }
    __syncthreads();

    // Phase C: vectorized writes
    if (tid < 48) {
        int h = tid >> 2, c4 = tid & 3;
        float4 qv = *reinterpret_cast<const float4*>(&ql_[h*16 + c4*4]);
        float4 kv = *reinterpret_cast<const float4*>(&kl_[h*16 + c4*4]);
        float4 vv = *reinterpret_cast<const float4*>(&vl_[h*16 + c4*4]);
        *reinterpret_cast<float4*>(&q_s[((size_t)h*NRES + n)*16 + c4*4]) = qv;
        k_t4[((size_t)h*4 + c4)*NRES + n] = kv;
        v_t4[((size_t)h*4 + c4)*NRES + n] = vv;
    } else if (tid >= 64 && tid < 100) {
        int u = tid - 64; int h = u / 3, e4 = u % 3;
        float4 kv = *reinterpret_cast<const float4*>(&wk_l[h*12 + e4*4]);
        wk_t4[((size_t)h*3 + e4)*NRES + n] = kv;
    } else if (tid >= 104 && tid < 140) {
        int u = tid - 104; int h = u / 3, e4 = u % 3;
        float4 qv = *reinterpret_cast<const float4*>(&wq_l[h*12 + e4*4]);
        *reinterpret_cast<float4*>(&wq[((size_t)h*NRES + n)*12 + e4*4]) = qv;
    } else if (tid >= 160 && tid < 232) {
        int u = tid - 160; int h = u / 6, e4 = u % 6;
        float4 vv = *reinterpret_cast<const float4*>(&wv_l[h*24 + e4*4]);
        wv_t4[((size_t)h*6 + e4)*NRES + n] = vv;
    } else if (tid >= 232 && tid < 244) {
        int h = tid - 232;
        qn[(size_t)h*NRES + n] = sq_part[h*4] + sq_part[h*4+1] + sq_part[h*4+2] + sq_part[h*4+3];
        kn[(size_t)h*NRES + n] = sk_part[h*4] + sk_part[h*4+1] + sk_part[h*4+2] + sk_part[h*4+3];
    }
}

// ---------------- Kernel 2: bias = z @ Wb + bb  -> [H][N][N] ----------------
__global__ __launch_bounds__(384) void k_bias(
    const float* __restrict__ z, const float* __restrict__ Wb,
    const float* __restrict__ bb, float* __restrict__ bias)
{
    __shared__ float zl[32*132];     // stride 132 (float4-aligned)
    __shared__ float wbl[12*128];    // transposed [h][c]
    __shared__ float bbl[12];
    int i = blockIdx.y, j0 = blockIdx.x * 32;
    int tid = threadIdx.x;
    for (int idx = tid; idx < 12*128; idx += 384) {
        int h = idx >> 7, c = idx & 127;
        wbl[idx] = Wb[c*12 + h];
    }
    if (tid < 12) bbl[tid] = bb[tid];
    for (int idx = tid; idx < 32*128; idx += 384) {
        int j = idx >> 7, c = idx & 127;
        zl[j*132 + c] = z[((size_t)i*NRES + j0 + j)*CZ + c];
    }
    __syncthreads();
    int h = tid / 32, j = tid % 32;
    float acc = bbl[h];
    #pragma unroll
    for (int c4 = 0; c4 < 32; ++c4) {
        float4 zv = *reinterpret_cast<const float4*>(&zl[j*132 + c4*4]);
        float4 wv = *reinterpret_cast<const float4*>(&wbl[h*128 + c4*4]);
        acc += zv.x*wv.x + zv.y*wv.y + zv.z*wv.z + zv.w*wv.w;
    }
    bias[((size_t)h*NRES + i)*NRES + j0 + j] = acc;
}

// ------- Kernel 3: attention row softmax (in-place att over bias) + v_out/o_pt -------
__global__ __launch_bounds__(256) void k_att(
    const float* __restrict__ q_s, const float4* __restrict__ k_t4,
    const float* __restrict__ wq, const float4* __restrict__ wk_t4,
    const float* __restrict__ qn, const float* __restrict__ kn,
    const float* __restrict__ hw,
    float* __restrict__ bias,       // in: bias, out: att
    const float4* __restrict__ v_t4, const float4* __restrict__ wv_t4,
    float* __restrict__ vout, float* __restrict__ opt)
{
    int i = blockIdx.x, h = blockIdx.y;
    int tid = threadIdx.x;
    __shared__ float ql[16], wql[12];
    __shared__ float att[NRES];
    __shared__ float red[8];
    __shared__ float sG, sQn;

    if (tid < 16) ql[tid] = q_s[((size_t)h*NRES + i)*16 + tid];
    else if (tid < 28) wql[tid-16] = wq[((size_t)h*NRES + i)*12 + (tid-16)];
    if (tid == 0) {
        sQn = qn[(size_t)h*NRES + i];
        float x = hw[h];
        float sp = (x > 20.f) ? x : log1pf(expf(x));
        sG = sp * W_C * 0.5f;
    }
    __syncthreads();
    float qn_i = sQn, gam = sG;

    float lg[2];
    #pragma unroll
    for (int m = 0; m < 2; ++m) {
        int j = tid + m*256;
        float qk = 0.f;
        #pragma unroll
        for (int c4 = 0; c4 < 4; ++c4) {
            float4 kv = k_t4[((size_t)h*4 + c4)*NRES + j];
            qk += ql[c4*4+0]*kv.x + ql[c4*4+1]*kv.y + ql[c4*4+2]*kv.z + ql[c4*4+3]*kv.w;
        }
        float dd = 0.f;
        #pragma unroll
        for (int e4 = 0; e4 < 3; ++e4) {
            float4 kv = wk_t4[((size_t)h*3 + e4)*NRES + j];
            dd += wql[e4*4+0]*kv.x + wql[e4*4+1]*kv.y + wql[e4*4+2]*kv.z + wql[e4*4+3]*kv.w;
        }
        float d2 = qn_i + kn[(size_t)h*NRES + j] - 2.f*dd;
        lg[m] = W_L * (qk + bias[((size_t)h*NRES + i)*NRES + j] - gam*d2);
    }

    int wave = tid >> 6, lane = tid & 63;
    // block max via wave shfl + 4-entry combine
    float mx = fmaxf(lg[0], lg[1]);
    #pragma unroll
    for (int d = 32; d > 0; d >>= 1) mx = fmaxf(mx, __shfl_xor(mx, d));
    if (lane == 0) red[wave] = mx;
    __syncthreads();
    mx = fmaxf(fmaxf(red[0], red[1]), fmaxf(red[2], red[3]));
    float e0 = __expf(lg[0]-mx), e1 = __expf(lg[1]-mx);
    float sm = e0 + e1;
    #pragma unroll
    for (int d = 32; d > 0; d >>= 1) sm += __shfl_xor(sm, d);
    if (lane == 0) red[4+wave] = sm;
    __syncthreads();
    float inv = 1.f / (red[4]+red[5]+red[6]+red[7]);
    float a0 = e0*inv, a1 = e1*inv;
    att[tid] = a0; att[tid+256] = a1;
    bias[((size_t)h*NRES + i)*NRES + tid]       = a0;
    bias[((size_t)h*NRES + i)*NRES + tid + 256] = a1;
    __syncthreads();

    // v_out (4 float4 rows) and o_pt (6 float4 rows): 10 groups over 4 waves
    for (int g = wave; g < 10; g += 4) {
        const float4* row = (g < 4) ? &v_t4[((size_t)h*4 + g)*NRES]
                                    : &wv_t4[((size_t)h*6 + (g-4))*NRES];
        float px = 0.f, py = 0.f, pz = 0.f, pw = 0.f;
        #pragma unroll
        for (int jj = 0; jj < 8; ++jj) {
            int j = lane + jj*64;
            float a = att[j];
            float4 r = row[j];
            px += a*r.x; py += a*r.y; pz += a*r.z; pw += a*r.w;
        }
        #pragma unroll
        for (int d = 32; d > 0; d >>= 1) {
            px += __shfl_down(px, d);
            py += __shfl_down(py, d);
            pz += __shfl_down(pz, d);
            pw += __shfl_down(pw, d);
        }
        if (lane == 0) {
            float4 r4 = make_float4(px, py, pz, pw);
            if (g < 4) *reinterpret_cast<float4*>(&vout[(size_t)i*HC + h*16 + g*4]) = r4;
            else       *reinterpret_cast<float4*>(&opt [(size_t)i*288 + h*24 + (g-4)*4]) = r4;
        }
    }
}

// ---------------- Kernel 4: pairwise_out = att @ z  per i ----------------
__global__ __launch_bounds__(256) void k_pair(
    const float* __restrict__ z, const float* __restrict__ att,
    float* __restrict__ pout)
{
    int i = blockIdx.x, tid = threadIdx.x;
    __shared__ float zl[64*129];
    __shared__ float al[12*64];
    int c = tid & 127, hh = tid >> 7;  // hh in {0,1}
    float acc[6] = {0,0,0,0,0,0};
    for (int j0 = 0; j0 < NRES; j0 += 64) {
        __syncthreads();
        for (int idx = tid; idx < 64*128; idx += 256) {
            int j = idx >> 7, cc = idx & 127;
            zl[j*129 + cc] = z[((size_t)i*NRES + j0 + j)*CZ + cc];
        }
        for (int idx = tid; idx < 12*64; idx += 256) {
            int h2 = idx >> 6, jj = idx & 63;
            al[h2*64 + jj] = att[((size_t)h2*NRES + i)*NRES + j0 + jj];
        }
        __syncthreads();
        for (int jj = 0; jj < 64; ++jj) {
            float zv = zl[jj*129 + c];
            #pragma unroll
            for (int m = 0; m < 6; ++m) {
                acc[m] += al[(hh + 2*m)*64 + jj] * zv;
            }
        }
    }
    #pragma unroll
    for (int m = 0; m < 6; ++m) {
        pout[(size_t)i*1536 + (hh + 2*m)*128 + c] = acc[m];
    }
}

// ---------------- Kernel 5: assemble cat and final projection ----------------
__global__ __launch_bounds__(384) void k_final(
    const float* __restrict__ vout, const float* __restrict__ opt,
    const float* __restrict__ pout, const float* __restrict__ T,
    const float* __restrict__ Wo, const float* __restrict__ bo,
    float* __restrict__ out)
{
    int i0 = blockIdx.x * 4, tid = threadIdx.x;
    __shared__ float cat[4][2112];
    for (int m = 0; m < 4; ++m) {
        int i = i0 + m;
        for (int f = tid; f < 192; f += 384)  cat[m][f] = vout[(size_t)i*HC + f];
        for (int f = tid; f < 1536; f += 384) cat[m][576 + f] = pout[(size_t)i*1536 + f];
        if (tid < 96) {
            int h = tid >> 3, p = tid & 7;
            float y0 = opt[(size_t)i*288 + h*24 + p*3 + 0] - T[i*16 + 0*4 + 3];
            float y1 = opt[(size_t)i*288 + h*24 + p*3 + 1] - T[i*16 + 1*4 + 3];
            float y2 = opt[(size_t)i*288 + h*24 + p*3 + 2] - T[i*16 + 2*4 + 3];
            float n2 = 0.f;
            #pragma unroll
            for (int x = 0; x < 3; ++x) {
                float w = T[i*16 + 0*4 + x]*y0 + T[i*16 + 1*4 + x]*y1 + T[i*16 + 2*4 + x]*y2;
                cat[m][192 + x*96 + h*8 + p] = w;
                n2 += w*w;
            }
            cat[m][480 + h*8 + p] = sqrtf(n2);
        }
    }
    __syncthreads();
    int o = tid;
    float acc0 = bo[o], acc1 = bo[o], acc2 = bo[o], acc3 = bo[o];
    for (int f = 0; f < 2112; ++f) {
        float w = Wo[(size_t)f*CS + o];
        acc0 += cat[0][f]*w;
        acc1 += cat[1][f]*w;
        acc2 += cat[2][f]*w;
        acc3 += cat[3][f]*w;
    }
    out[(size_t)(i0+0)*CS + o] = acc0;
    out[(size_t)(i0+1)*CS + o] = acc1;
    out[(size_t)(i0+2)*CS + o] = acc2;
    out[(size_t)(i0+3)*CS + o] = acc3;
}

// ---------------- launch ----------------
extern "C" void kernel_launch(void* const* d_in, const int* in_sizes, int n_in,
                              void* d_out, int out_size, void* d_ws, size_t ws_size,
                              hipStream_t stream)
{
    const float* s   = (const float*)d_in[0];
    const float* z   = (const float*)d_in[1];
    const float* T   = (const float*)d_in[2];
    const float* Wq  = (const float*)d_in[3];  const float* bq  = (const float*)d_in[4];
    const float* Wk  = (const float*)d_in[5];  const float* bk  = (const float*)d_in[6];
    const float* Wv  = (const float*)d_in[7];  const float* bv  = (const float*)d_in[8];
    const float* Wqp = (const float*)d_in[9];  const float* bqp = (const float*)d_in[10];
    const float* Wkp = (const float*)d_in[11]; const float* bkp = (const float*)d_in[12];
    const float* Wvp = (const float*)d_in[13]; const float* bvp = (const float*)d_in[14];
    const float* Wb  = (const float*)d_in[15]; const float* bb  = (const float*)d_in[16];
    const float* Wo  = (const float*)d_in[17]; const float* bo  = (const float*)d_in[18];
    const float* hw  = (const float*)d_in[19];
    float* out = (float*)d_out;
    float* ws  = (float*)d_ws;

    // workspace layout (floats)
    size_t off = 0;
    float* q_s  = ws + off; off += (size_t)NH*NRES*CC;      // 98304
    float* k_t  = ws + off; off += (size_t)NH*NRES*CC;
    float* v_t  = ws + off; off += (size_t)NH*NRES*CC;
    float* wq   = ws + off; off += (size_t)NH*NRES*12;      // 73728
    float* wk_t = ws + off; off += (size_t)NH*NRES*12;
    float* wv_t = ws + off; off += (size_t)NH*NRES*24;      // 147456
    float* qn   = ws + off; off += (size_t)NH*NRES;
    float* kn   = ws + off; off += (size_t)NH*NRES;
    float* bias = ws + off; off += (size_t)NH*NRES*NRES;    // 3.1M (also att, in-place)
    float* vout = ws + off; off += (size_t)NRES*HC;
    float* opt  = ws + off; off += (size_t)NRES*288;
    float* pout = ws + off; off += (size_t)NRES*1536;

    k_proj<<<dim3(NRES), dim3(256), 0, stream>>>(
        s, T, Wq, bq, Wk, bk, Wv, bv, Wqp, bqp, Wkp, bkp, Wvp, bvp,
        q_s, (float4*)k_t, (float4*)v_t, wq, (float4*)wk_t, (float4*)wv_t, qn, kn);

    k_bias<<<dim3(16, NRES), dim3(384), 0, stream>>>(z, Wb, bb, bias);

    k_att<<<dim3(NRES, NH), dim3(256), 0, stream>>>(
        q_s, (const float4*)k_t, wq, (const float4*)wk_t, qn, kn, hw, bias,
        (const float4*)v_t, (const float4*)wv_t, vout, opt);

    k_pair<<<dim3(NRES), dim3(256), 0, stream>>>(z, bias, pout);

    k_final<<<dim3(NRES/4), dim3(384), 0, stream>>>(vout, opt, pout, T, Wo, bo, out);
}

// Round 3
// 276.543 us; speedup vs baseline: 2.2130x; 1.2884x over previous
//
#include <hip/hip_runtime.h>
#include <hip/hip_bf16.h>
#include <math.h>

// Problem constants
#define NRES 512
#define CS 384
#define CZ 128
#define NH 12
#define CC 16
#define NQP 4
#define NPV 8
#define HC (NH*CC)        // 192
#define FTOT 1152         // 192*3 + 144*2 + 288
#define W_C 0.23570226039551584f   // sqrt(2/(9*4))
#define W_L 0.5773502691896258f    // sqrt(1/3)

// ---------------- Kernel 1a: all projections as one GEMM ----------------
// P[n][f], f-layout: [0,192)=q, [192,384)=k, [384,576)=v,
//                    [576,720)=qp raw, [720,864)=kp raw, [864,1152)=vp raw
// Each thread: one f column, 8 residues. s-row operands are wave-uniform ->
// scalar (SMEM) loads; weight load coalesced across lanes.
__global__ __launch_bounds__(384) void k_gemm(
    const float* __restrict__ s,
    const float* __restrict__ Wq, const float* __restrict__ bq,
    const float* __restrict__ Wk, const float* __restrict__ bk,
    const float* __restrict__ Wv, const float* __restrict__ bv,
    const float* __restrict__ Wqp, const float* __restrict__ bqp,
    const float* __restrict__ Wkp, const float* __restrict__ bkp,
    const float* __restrict__ Wvp, const float* __restrict__ bvp,
    float* __restrict__ p_raw)
{
    int r0 = blockIdx.x * 8;
    int f  = blockIdx.y * 384 + threadIdx.x;
    const float* W; const float* bia; int col; int stride;
    if      (f < 192) { W = Wq;  bia = bq;  col = f;       stride = 192; }
    else if (f < 384) { W = Wk;  bia = bk;  col = f - 192; stride = 192; }
    else if (f < 576) { W = Wv;  bia = bv;  col = f - 384; stride = 192; }
    else if (f < 720) { W = Wqp; bia = bqp; col = f - 576; stride = 144; }
    else if (f < 864) { W = Wkp; bia = bkp; col = f - 720; stride = 144; }
    else              { W = Wvp; bia = bvp; col = f - 864; stride = 288; }

    float acc[8];
    float b0 = bia[col];
    #pragma unroll
    for (int j = 0; j < 8; ++j) acc[j] = b0;

    const float* srow = s + (size_t)r0 * CS;
    #pragma unroll 4
    for (int i = 0; i < CS; ++i) {
        float w = W[(size_t)i * stride + col];
        #pragma unroll
        for (int j = 0; j < 8; ++j) acc[j] = fmaf(w, srow[j*CS + i], acc[j]);
    }
    #pragma unroll
    for (int j = 0; j < 8; ++j) p_raw[(size_t)(r0 + j)*FTOT + f] = acc[j];
}

// ---------------- Kernel 1b: warp + transpose layouts ----------------
// Outputs:
//   q_s  [h][n][16] (pre-scaled by 1/4)
//   k_t4 [(h*4+c4)*512 + n] float4 ; v_t4 same
//   wq   [h][n][12]
//   wk_t4[(h*3+e4)*512 + n] float4 ; wv_t4 [(h*6+e4)*512 + n] float4
//   qn/kn[h][n]
__global__ __launch_bounds__(256) void k_post(
    const float* __restrict__ p_raw, const float* __restrict__ T,
    float* __restrict__ q_s, float4* __restrict__ k_t4, float4* __restrict__ v_t4,
    float* __restrict__ wq, float4* __restrict__ wk_t4, float4* __restrict__ wv_t4,
    float* __restrict__ qn, float* __restrict__ kn)
{
    int n = blockIdx.x;
    int tid = threadIdx.x;
    __shared__ float pl[FTOT];
    __shared__ float Rl[9], tl[3];
    __shared__ float wq_l[144], wk_l[144], wv_l[288];
    __shared__ float sq_part[48], sk_part[48];

    for (int idx = tid; idx < FTOT/4; idx += 256)
        *reinterpret_cast<float4*>(&pl[idx*4]) =
            *reinterpret_cast<const float4*>(&p_raw[(size_t)n*FTOT + idx*4]);
    if (tid < 9)  Rl[tid] = T[n*16 + (tid/3)*4 + (tid%3)];
    if (tid >= 16 && tid < 19) tl[tid-16] = T[n*16 + (tid-16)*4 + 3];
    __syncthreads();

    // warp qp/kp: 48 (h,p) pairs; vp: 96 (h,p) pairs
    if (tid < 48) {
        int h = tid >> 2, p = tid & 3;
        float qy0 = pl[576 + 0*48 + h*4 + p], qy1 = pl[576 + 1*48 + h*4 + p], qy2 = pl[576 + 2*48 + h*4 + p];
        float ky0 = pl[720 + 0*48 + h*4 + p], ky1 = pl[720 + 1*48 + h*4 + p], ky2 = pl[720 + 2*48 + h*4 + p];
        float qs2 = 0.f, ks2 = 0.f;
        #pragma unroll
        for (int x = 0; x < 3; ++x) {
            float wqv = Rl[x*3+0]*qy0 + Rl[x*3+1]*qy1 + Rl[x*3+2]*qy2 + tl[x];
            float wkv = Rl[x*3+0]*ky0 + Rl[x*3+1]*ky1 + Rl[x*3+2]*ky2 + tl[x];
            wq_l[h*12 + p*3 + x] = wqv;
            wk_l[h*12 + p*3 + x] = wkv;
            qs2 += wqv*wqv; ks2 += wkv*wkv;
        }
        sq_part[tid] = qs2; sk_part[tid] = ks2;
    } else if (tid >= 64 && tid < 160) {
        int u = tid - 64; int h = u >> 3, p = u & 7;
        float y0 = pl[864 + 0*96 + h*8 + p], y1 = pl[864 + 1*96 + h*8 + p], y2 = pl[864 + 2*96 + h*8 + p];
        #pragma unroll
        for (int x = 0; x < 3; ++x) {
            wv_l[h*24 + p*3 + x] = Rl[x*3+0]*y0 + Rl[x*3+1]*y1 + Rl[x*3+2]*y2 + tl[x];
        }
    }
    __syncthreads();

    // vectorized writes
    if (tid < 48) {
        int h = tid >> 2, c4 = tid & 3;
        float4 qv = *reinterpret_cast<const float4*>(&pl[h*16 + c4*4]);
        qv.x *= 0.25f; qv.y *= 0.25f; qv.z *= 0.25f; qv.w *= 0.25f;
        float4 kv = *reinterpret_cast<const float4*>(&pl[192 + h*16 + c4*4]);
        float4 vv = *reinterpret_cast<const float4*>(&pl[384 + h*16 + c4*4]);
        *reinterpret_cast<float4*>(&q_s[((size_t)h*NRES + n)*16 + c4*4]) = qv;
        k_t4[((size_t)h*4 + c4)*NRES + n] = kv;
        v_t4[((size_t)h*4 + c4)*NRES + n] = vv;
    } else if (tid >= 64 && tid < 100) {
        int u = tid - 64; int h = u / 3, e4 = u % 3;
        float4 kv = *reinterpret_cast<const float4*>(&wk_l[h*12 + e4*4]);
        wk_t4[((size_t)h*3 + e4)*NRES + n] = kv;
    } else if (tid >= 104 && tid < 140) {
        int u = tid - 104; int h = u / 3, e4 = u % 3;
        float4 qv = *reinterpret_cast<const float4*>(&wq_l[h*12 + e4*4]);
        *reinterpret_cast<float4*>(&wq[((size_t)h*NRES + n)*12 + e4*4]) = qv;
    } else if (tid >= 160 && tid < 232) {
        int u = tid - 160; int h = u / 6, e4 = u % 6;
        float4 vv = *reinterpret_cast<const float4*>(&wv_l[h*24 + e4*4]);
        wv_t4[((size_t)h*6 + e4)*NRES + n] = vv;
    } else if (tid >= 232 && tid < 244) {
        int h = tid - 232;
        qn[(size_t)h*NRES + n] = sq_part[h*4] + sq_part[h*4+1] + sq_part[h*4+2] + sq_part[h*4+3];
        kn[(size_t)h*NRES + n] = sk_part[h*4] + sk_part[h*4+1] + sk_part[h*4+2] + sk_part[h*4+3];
    }
}

// ---------------- Kernel 2: bias = z @ Wb + bb  -> [H][N][N] ----------------
__global__ __launch_bounds__(384) void k_bias(
    const float* __restrict__ z, const float* __restrict__ Wb,
    const float* __restrict__ bb, float* __restrict__ bias)
{
    __shared__ float zl[32*132];     // stride 132 (float4-aligned)
    __shared__ float wbl[12*128];    // transposed [h][c]
    __shared__ float bbl[12];
    int i = blockIdx.y, j0 = blockIdx.x * 32;
    int tid = threadIdx.x;
    for (int idx = tid; idx < 12*128; idx += 384) {
        int h = idx >> 7, c = idx & 127;
        wbl[idx] = Wb[c*12 + h];
    }
    if (tid < 12) bbl[tid] = bb[tid];
    for (int idx = tid; idx < 32*128; idx += 384) {
        int j = idx >> 7, c = idx & 127;
        zl[j*132 + c] = z[((size_t)i*NRES + j0 + j)*CZ + c];
    }
    __syncthreads();
    int h = tid / 32, j = tid % 32;
    float acc = bbl[h];
    #pragma unroll
    for (int c4 = 0; c4 < 32; ++c4) {
        float4 zv = *reinterpret_cast<const float4*>(&zl[j*132 + c4*4]);
        float4 wv = *reinterpret_cast<const float4*>(&wbl[h*128 + c4*4]);
        acc += zv.x*wv.x + zv.y*wv.y + zv.z*wv.z + zv.w*wv.w;
    }
    bias[((size_t)h*NRES + i)*NRES + j0 + j] = acc;
}

// ------- Kernel 3: attention row softmax (in-place att over bias) + v_out/o_pt -------
__global__ __launch_bounds__(256) void k_att(
    const float* __restrict__ q_s, const float4* __restrict__ k_t4,
    const float* __restrict__ wq, const float4* __restrict__ wk_t4,
    const float* __restrict__ qn, const float* __restrict__ kn,
    const float* __restrict__ hw,
    float* __restrict__ bias,       // in: bias, out: att
    const float4* __restrict__ v_t4, const float4* __restrict__ wv_t4,
    float* __restrict__ vout, float* __restrict__ opt)
{
    int i = blockIdx.x, h = blockIdx.y;
    int tid = threadIdx.x;
    __shared__ float ql[16], wql[12];
    __shared__ float att[NRES];
    __shared__ float red[8];
    __shared__ float sG, sQn;

    if (tid < 16) ql[tid] = q_s[((size_t)h*NRES + i)*16 + tid];
    else if (tid < 28) wql[tid-16] = wq[((size_t)h*NRES + i)*12 + (tid-16)];
    if (tid == 0) {
        sQn = qn[(size_t)h*NRES + i];
        float x = hw[h];
        float sp = (x > 20.f) ? x : log1pf(expf(x));
        sG = sp * W_C * 0.5f;
    }
    __syncthreads();
    float qn_i = sQn, gam = sG;

    float lg[2];
    #pragma unroll
    for (int m = 0; m < 2; ++m) {
        int j = tid + m*256;
        float qk = 0.f;
        #pragma unroll
        for (int c4 = 0; c4 < 4; ++c4) {
            float4 kv = k_t4[((size_t)h*4 + c4)*NRES + j];
            qk += ql[c4*4+0]*kv.x + ql[c4*4+1]*kv.y + ql[c4*4+2]*kv.z + ql[c4*4+3]*kv.w;
        }
        float dd = 0.f;
        #pragma unroll
        for (int e4 = 0; e4 < 3; ++e4) {
            float4 kv = wk_t4[((size_t)h*3 + e4)*NRES + j];
            dd += wql[e4*4+0]*kv.x + wql[e4*4+1]*kv.y + wql[e4*4+2]*kv.z + wql[e4*4+3]*kv.w;
        }
        float d2 = qn_i + kn[(size_t)h*NRES + j] - 2.f*dd;
        lg[m] = W_L * (qk + bias[((size_t)h*NRES + i)*NRES + j] - gam*d2);
    }

    int wave = tid >> 6, lane = tid & 63;
    float mx = fmaxf(lg[0], lg[1]);
    #pragma unroll
    for (int d = 32; d > 0; d >>= 1) mx = fmaxf(mx, __shfl_xor(mx, d));
    if (lane == 0) red[wave] = mx;
    __syncthreads();
    mx = fmaxf(fmaxf(red[0], red[1]), fmaxf(red[2], red[3]));
    float e0 = __expf(lg[0]-mx), e1 = __expf(lg[1]-mx);
    float sm = e0 + e1;
    #pragma unroll
    for (int d = 32; d > 0; d >>= 1) sm += __shfl_xor(sm, d);
    if (lane == 0) red[4+wave] = sm;
    __syncthreads();
    float inv = 1.f / (red[4]+red[5]+red[6]+red[7]);
    float a0 = e0*inv, a1 = e1*inv;
    att[tid] = a0; att[tid+256] = a1;
    bias[((size_t)h*NRES + i)*NRES + tid]       = a0;
    bias[((size_t)h*NRES + i)*NRES + tid + 256] = a1;
    __syncthreads();

    for (int g = wave; g < 10; g += 4) {
        const float4* row = (g < 4) ? &v_t4[((size_t)h*4 + g)*NRES]
                                    : &wv_t4[((size_t)h*6 + (g-4))*NRES];
        float px = 0.f, py = 0.f, pz = 0.f, pw = 0.f;
        #pragma unroll
        for (int jj = 0; jj < 8; ++jj) {
            int j = lane + jj*64;
            float a = att[j];
            float4 r = row[j];
            px += a*r.x; py += a*r.y; pz += a*r.z; pw += a*r.w;
        }
        #pragma unroll
        for (int d = 32; d > 0; d >>= 1) {
            px += __shfl_down(px, d);
            py += __shfl_down(py, d);
            pz += __shfl_down(pz, d);
            pw += __shfl_down(pw, d);
        }
        if (lane == 0) {
            float4 r4 = make_float4(px, py, pz, pw);
            if (g < 4) *reinterpret_cast<float4*>(&vout[(size_t)i*HC + h*16 + g*4]) = r4;
            else       *reinterpret_cast<float4*>(&opt [(size_t)i*288 + h*24 + (g-4)*4]) = r4;
        }
    }
}

// ---------------- Kernel 4: pairwise_out = att @ z  per i ----------------
__global__ __launch_bounds__(256) void k_pair(
    const float* __restrict__ z, const float* __restrict__ att,
    float* __restrict__ pout)
{
    int i = blockIdx.x, tid = threadIdx.x;
    __shared__ float zl[64*129];
    __shared__ float al[12*64];
    int c = tid & 127, hh = tid >> 7;  // hh in {0,1}
    float acc[6] = {0,0,0,0,0,0};
    for (int j0 = 0; j0 < NRES; j0 += 64) {
        __syncthreads();
        for (int idx = tid; idx < 64*128; idx += 256) {
            int j = idx >> 7, cc = idx & 127;
            zl[j*129 + cc] = z[((size_t)i*NRES + j0 + j)*CZ + cc];
        }
        for (int idx = tid; idx < 12*64; idx += 256) {
            int h2 = idx >> 6, jj = idx & 63;
            al[h2*64 + jj] = att[((size_t)h2*NRES + i)*NRES + j0 + jj];
        }
        __syncthreads();
        for (int jj = 0; jj < 64; ++jj) {
            float zv = zl[jj*129 + c];
            #pragma unroll
            for (int m = 0; m < 6; ++m) {
                acc[m] += al[(hh + 2*m)*64 + jj] * zv;
            }
        }
    }
    #pragma unroll
    for (int m = 0; m < 6; ++m) {
        pout[(size_t)i*1536 + (hh + 2*m)*128 + c] = acc[m];
    }
}

// ---------------- Kernel 5: assemble cat and final projection ----------------
__global__ __launch_bounds__(384) void k_final(
    const float* __restrict__ vout, const float* __restrict__ opt,
    const float* __restrict__ pout, const float* __restrict__ T,
    const float* __restrict__ Wo, const float* __restrict__ bo,
    float* __restrict__ out)
{
    int i0 = blockIdx.x * 4, tid = threadIdx.x;
    __shared__ float cat[4][2112];
    for (int m = 0; m < 4; ++m) {
        int i = i0 + m;
        for (int f = tid; f < 192; f += 384)  cat[m][f] = vout[(size_t)i*HC + f];
        for (int f = tid; f < 1536; f += 384) cat[m][576 + f] = pout[(size_t)i*1536 + f];
        if (tid < 96) {
            int h = tid >> 3, p = tid & 7;
            float y0 = opt[(size_t)i*288 + h*24 + p*3 + 0] - T[i*16 + 0*4 + 3];
            float y1 = opt[(size_t)i*288 + h*24 + p*3 + 1] - T[i*16 + 1*4 + 3];
            float y2 = opt[(size_t)i*288 + h*24 + p*3 + 2] - T[i*16 + 2*4 + 3];
            float n2 = 0.f;
            #pragma unroll
            for (int x = 0; x < 3; ++x) {
                float w = T[i*16 + 0*4 + x]*y0 + T[i*16 + 1*4 + x]*y1 + T[i*16 + 2*4 + x]*y2;
                cat[m][192 + x*96 + h*8 + p] = w;
                n2 += w*w;
            }
            cat[m][480 + h*8 + p] = sqrtf(n2);
        }
    }
    __syncthreads();
    int o = tid;
    float acc0 = bo[o], acc1 = bo[o], acc2 = bo[o], acc3 = bo[o];
    for (int f = 0; f < 2112; ++f) {
        float w = Wo[(size_t)f*CS + o];
        acc0 += cat[0][f]*w;
        acc1 += cat[1][f]*w;
        acc2 += cat[2][f]*w;
        acc3 += cat[3][f]*w;
    }
    out[(size_t)(i0+0)*CS + o] = acc0;
    out[(size_t)(i0+1)*CS + o] = acc1;
    out[(size_t)(i0+2)*CS + o] = acc2;
    out[(size_t)(i0+3)*CS + o] = acc3;
}

// ---------------- launch ----------------
extern "C" void kernel_launch(void* const* d_in, const int* in_sizes, int n_in,
                              void* d_out, int out_size, void* d_ws, size_t ws_size,
                              hipStream_t stream)
{
    const float* s   = (const float*)d_in[0];
    const float* z   = (const float*)d_in[1];
    const float* T   = (const float*)d_in[2];
    const float* Wq  = (const float*)d_in[3];  const float* bq  = (const float*)d_in[4];
    const float* Wk  = (const float*)d_in[5];  const float* bk  = (const float*)d_in[6];
    const float* Wv  = (const float*)d_in[7];  const float* bv  = (const float*)d_in[8];
    const float* Wqp = (const float*)d_in[9];  const float* bqp = (const float*)d_in[10];
    const float* Wkp = (const float*)d_in[11]; const float* bkp = (const float*)d_in[12];
    const float* Wvp = (const float*)d_in[13]; const float* bvp = (const float*)d_in[14];
    const float* Wb  = (const float*)d_in[15]; const float* bb  = (const float*)d_in[16];
    const float* Wo  = (const float*)d_in[17]; const float* bo  = (const float*)d_in[18];
    const float* hw  = (const float*)d_in[19];
    float* out = (float*)d_out;
    float* ws  = (float*)d_ws;

    // workspace layout (floats)
    size_t off = 0;
    float* q_s  = ws + off; off += (size_t)NH*NRES*CC;      // 98304
    float* k_t  = ws + off; off += (size_t)NH*NRES*CC;
    float* v_t  = ws + off; off += (size_t)NH*NRES*CC;
    float* wq   = ws + off; off += (size_t)NH*NRES*12;      // 73728
    float* wk_t = ws + off; off += (size_t)NH*NRES*12;
    float* wv_t = ws + off; off += (size_t)NH*NRES*24;      // 147456
    float* qn   = ws + off; off += (size_t)NH*NRES;
    float* kn   = ws + off; off += (size_t)NH*NRES;
    float* bias = ws + off; off += (size_t)NH*NRES*NRES;    // 3.1M (also att, in-place)
    float* vout = ws + off; off += (size_t)NRES*HC;
    float* opt  = ws + off; off += (size_t)NRES*288;
    float* pout = ws + off; off += (size_t)NRES*1536;
    float* praw = ws + off; off += (size_t)NRES*FTOT;       // 589824

    k_gemm<<<dim3(NRES/8, 3), dim3(384), 0, stream>>>(
        s, Wq, bq, Wk, bk, Wv, bv, Wqp, bqp, Wkp, bkp, Wvp, bvp, praw);

    k_post<<<dim3(NRES), dim3(256), 0, stream>>>(
        praw, T, q_s, (float4*)k_t, (float4*)v_t, wq, (float4*)wk_t, (float4*)wv_t, qn, kn);

    k_bias<<<dim3(16, NRES), dim3(384), 0, stream>>>(z, Wb, bb, bias);

    k_att<<<dim3(NRES, NH), dim3(256), 0, stream>>>(
        q_s, (const float4*)k_t, wq, (const float4*)wk_t, qn, kn, hw, bias,
        (const float4*)v_t, (const float4*)wv_t, vout, opt);

    k_pair<<<dim3(NRES), dim3(256), 0, stream>>>(z, bias, pout);

    k_final<<<dim3(NRES/4), dim3(384), 0, stream>>>(vout, opt, pout, T, Wo, bo, out);
}

// Round 4
// 206.818 us; speedup vs baseline: 2.9591x; 1.3371x over previous
//
#include <hip/hip_runtime.h>
#include <hip/hip_bf16.h>
#include <math.h>

// Problem constants
#define NRES 512
#define CS 384
#define CZ 128
#define NH 12
#define CC 16
#define NQP 4
#define NPV 8
#define HC (NH*CC)        // 192
#define FTOT 1152         // 192*3 + 144*2 + 288
#define CATF 2112         // 192 + 288 + 96 + 1536
#define FSPLIT 8
#define FCHUNK 264        // 2112/8
#define W_C 0.23570226039551584f   // sqrt(2/(9*4))
#define W_L 0.5773502691896258f    // sqrt(1/3)

// ---------------- Kernel 1a: all projections as one GEMM ----------------
__global__ __launch_bounds__(384) void k_gemm(
    const float* __restrict__ s,
    const float* __restrict__ Wq, const float* __restrict__ bq,
    const float* __restrict__ Wk, const float* __restrict__ bk,
    const float* __restrict__ Wv, const float* __restrict__ bv,
    const float* __restrict__ Wqp, const float* __restrict__ bqp,
    const float* __restrict__ Wkp, const float* __restrict__ bkp,
    const float* __restrict__ Wvp, const float* __restrict__ bvp,
    float* __restrict__ p_raw)
{
    int r0 = blockIdx.x * 8;
    int f  = blockIdx.y * 384 + threadIdx.x;
    const float* W; const float* bia; int col; int stride;
    if      (f < 192) { W = Wq;  bia = bq;  col = f;       stride = 192; }
    else if (f < 384) { W = Wk;  bia = bk;  col = f - 192; stride = 192; }
    else if (f < 576) { W = Wv;  bia = bv;  col = f - 384; stride = 192; }
    else if (f < 720) { W = Wqp; bia = bqp; col = f - 576; stride = 144; }
    else if (f < 864) { W = Wkp; bia = bkp; col = f - 720; stride = 144; }
    else              { W = Wvp; bia = bvp; col = f - 864; stride = 288; }

    float acc[8];
    float b0 = bia[col];
    #pragma unroll
    for (int j = 0; j < 8; ++j) acc[j] = b0;

    const float* srow = s + (size_t)r0 * CS;
    #pragma unroll 4
    for (int i = 0; i < CS; ++i) {
        float w = W[(size_t)i * stride + col];
        #pragma unroll
        for (int j = 0; j < 8; ++j) acc[j] = fmaf(w, srow[j*CS + i], acc[j]);
    }
    #pragma unroll
    for (int j = 0; j < 8; ++j) p_raw[(size_t)(r0 + j)*FTOT + f] = acc[j];
}

// ---------------- Kernel 1b: warp + transpose layouts ----------------
__global__ __launch_bounds__(256) void k_post(
    const float* __restrict__ p_raw, const float* __restrict__ T,
    float* __restrict__ q_s, float4* __restrict__ k_t4, float4* __restrict__ v_t4,
    float* __restrict__ wq, float4* __restrict__ wk_t4, float4* __restrict__ wv_t4,
    float* __restrict__ qn, float* __restrict__ kn)
{
    int n = blockIdx.x;
    int tid = threadIdx.x;
    __shared__ float pl[FTOT];
    __shared__ float Rl[9], tl[3];
    __shared__ float wq_l[144], wk_l[144], wv_l[288];
    __shared__ float sq_part[48], sk_part[48];

    for (int idx = tid; idx < FTOT/4; idx += 256)
        *reinterpret_cast<float4*>(&pl[idx*4]) =
            *reinterpret_cast<const float4*>(&p_raw[(size_t)n*FTOT + idx*4]);
    if (tid < 9)  Rl[tid] = T[n*16 + (tid/3)*4 + (tid%3)];
    if (tid >= 16 && tid < 19) tl[tid-16] = T[n*16 + (tid-16)*4 + 3];
    __syncthreads();

    if (tid < 48) {
        int h = tid >> 2, p = tid & 3;
        float qy0 = pl[576 + 0*48 + h*4 + p], qy1 = pl[576 + 1*48 + h*4 + p], qy2 = pl[576 + 2*48 + h*4 + p];
        float ky0 = pl[720 + 0*48 + h*4 + p], ky1 = pl[720 + 1*48 + h*4 + p], ky2 = pl[720 + 2*48 + h*4 + p];
        float qs2 = 0.f, ks2 = 0.f;
        #pragma unroll
        for (int x = 0; x < 3; ++x) {
            float wqv = Rl[x*3+0]*qy0 + Rl[x*3+1]*qy1 + Rl[x*3+2]*qy2 + tl[x];
            float wkv = Rl[x*3+0]*ky0 + Rl[x*3+1]*ky1 + Rl[x*3+2]*ky2 + tl[x];
            wq_l[h*12 + p*3 + x] = wqv;
            wk_l[h*12 + p*3 + x] = wkv;
            qs2 += wqv*wqv; ks2 += wkv*wkv;
        }
        sq_part[tid] = qs2; sk_part[tid] = ks2;
    } else if (tid >= 64 && tid < 160) {
        int u = tid - 64; int h = u >> 3, p = u & 7;
        float y0 = pl[864 + 0*96 + h*8 + p], y1 = pl[864 + 1*96 + h*8 + p], y2 = pl[864 + 2*96 + h*8 + p];
        #pragma unroll
        for (int x = 0; x < 3; ++x) {
            wv_l[h*24 + p*3 + x] = Rl[x*3+0]*y0 + Rl[x*3+1]*y1 + Rl[x*3+2]*y2 + tl[x];
        }
    }
    __syncthreads();

    if (tid < 48) {
        int h = tid >> 2, c4 = tid & 3;
        float4 qv = *reinterpret_cast<const float4*>(&pl[h*16 + c4*4]);
        qv.x *= 0.25f; qv.y *= 0.25f; qv.z *= 0.25f; qv.w *= 0.25f;
        float4 kv = *reinterpret_cast<const float4*>(&pl[192 + h*16 + c4*4]);
        float4 vv = *reinterpret_cast<const float4*>(&pl[384 + h*16 + c4*4]);
        *reinterpret_cast<float4*>(&q_s[((size_t)h*NRES + n)*16 + c4*4]) = qv;
        k_t4[((size_t)h*4 + c4)*NRES + n] = kv;
        v_t4[((size_t)h*4 + c4)*NRES + n] = vv;
    } else if (tid >= 64 && tid < 100) {
        int u = tid - 64; int h = u / 3, e4 = u % 3;
        float4 kv = *reinterpret_cast<const float4*>(&wk_l[h*12 + e4*4]);
        wk_t4[((size_t)h*3 + e4)*NRES + n] = kv;
    } else if (tid >= 104 && tid < 140) {
        int u = tid - 104; int h = u / 3, e4 = u % 3;
        float4 qv = *reinterpret_cast<const float4*>(&wq_l[h*12 + e4*4]);
        *reinterpret_cast<float4*>(&wq[((size_t)h*NRES + n)*12 + e4*4]) = qv;
    } else if (tid >= 160 && tid < 232) {
        int u = tid - 160; int h = u / 6, e4 = u % 6;
        float4 vv = *reinterpret_cast<const float4*>(&wv_l[h*24 + e4*4]);
        wv_t4[((size_t)h*6 + e4)*NRES + n] = vv;
    } else if (tid >= 232 && tid < 244) {
        int h = tid - 232;
        qn[(size_t)h*NRES + n] = sq_part[h*4] + sq_part[h*4+1] + sq_part[h*4+2] + sq_part[h*4+3];
        kn[(size_t)h*NRES + n] = sk_part[h*4] + sk_part[h*4+1] + sk_part[h*4+2] + sk_part[h*4+3];
    }
}

// ---------------- Kernel 2: bias = z @ Wb + bb  -> [H][N][N] ----------------
__global__ __launch_bounds__(384) void k_bias(
    const float* __restrict__ z, const float* __restrict__ Wb,
    const float* __restrict__ bb, float* __restrict__ bias)
{
    __shared__ float zl[32*132];
    __shared__ float wbl[12*128];
    __shared__ float bbl[12];
    int i = blockIdx.y, j0 = blockIdx.x * 32;
    int tid = threadIdx.x;
    for (int idx = tid; idx < 12*128; idx += 384) {
        int h = idx >> 7, c = idx & 127;
        wbl[idx] = Wb[c*12 + h];
    }
    if (tid < 12) bbl[tid] = bb[tid];
    for (int idx = tid; idx < 32*128; idx += 384) {
        int j = idx >> 7, c = idx & 127;
        zl[j*132 + c] = z[((size_t)i*NRES + j0 + j)*CZ + c];
    }
    __syncthreads();
    int h = tid / 32, j = tid % 32;
    float acc = bbl[h];
    #pragma unroll
    for (int c4 = 0; c4 < 32; ++c4) {
        float4 zv = *reinterpret_cast<const float4*>(&zl[j*132 + c4*4]);
        float4 wv = *reinterpret_cast<const float4*>(&wbl[h*128 + c4*4]);
        acc += zv.x*wv.x + zv.y*wv.y + zv.z*wv.z + zv.w*wv.w;
    }
    bias[((size_t)h*NRES + i)*NRES + j0 + j] = acc;
}

// ------- Kernel 3: att softmax (in-place over bias) + v_out + o_pt transform -> cat -------
__global__ __launch_bounds__(256) void k_att(
    const float* __restrict__ q_s, const float4* __restrict__ k_t4,
    const float* __restrict__ wq, const float4* __restrict__ wk_t4,
    const float* __restrict__ qn, const float* __restrict__ kn,
    const float* __restrict__ hw, const float* __restrict__ T,
    float* __restrict__ bias,       // in: bias, out: att
    const float4* __restrict__ v_t4, const float4* __restrict__ wv_t4,
    float* __restrict__ cat)
{
    int i = blockIdx.x, h = blockIdx.y;
    int tid = threadIdx.x;
    __shared__ float ql[16], wql[12];
    __shared__ float att[NRES];
    __shared__ float red[8];
    __shared__ float optl[24];
    __shared__ float sG, sQn;

    if (tid < 16) ql[tid] = q_s[((size_t)h*NRES + i)*16 + tid];
    else if (tid < 28) wql[tid-16] = wq[((size_t)h*NRES + i)*12 + (tid-16)];
    if (tid == 0) {
        sQn = qn[(size_t)h*NRES + i];
        float x = hw[h];
        float sp = (x > 20.f) ? x : log1pf(expf(x));
        sG = sp * W_C * 0.5f;
    }
    __syncthreads();
    float qn_i = sQn, gam = sG;

    float lg[2];
    #pragma unroll
    for (int m = 0; m < 2; ++m) {
        int j = tid + m*256;
        float qk = 0.f;
        #pragma unroll
        for (int c4 = 0; c4 < 4; ++c4) {
            float4 kv = k_t4[((size_t)h*4 + c4)*NRES + j];
            qk += ql[c4*4+0]*kv.x + ql[c4*4+1]*kv.y + ql[c4*4+2]*kv.z + ql[c4*4+3]*kv.w;
        }
        float dd = 0.f;
        #pragma unroll
        for (int e4 = 0; e4 < 3; ++e4) {
            float4 kv = wk_t4[((size_t)h*3 + e4)*NRES + j];
            dd += wql[e4*4+0]*kv.x + wql[e4*4+1]*kv.y + wql[e4*4+2]*kv.z + wql[e4*4+3]*kv.w;
        }
        float d2 = qn_i + kn[(size_t)h*NRES + j] - 2.f*dd;
        lg[m] = W_L * (qk + bias[((size_t)h*NRES + i)*NRES + j] - gam*d2);
    }

    int wave = tid >> 6, lane = tid & 63;
    float mx = fmaxf(lg[0], lg[1]);
    #pragma unroll
    for (int d = 32; d > 0; d >>= 1) mx = fmaxf(mx, __shfl_xor(mx, d));
    if (lane == 0) red[wave] = mx;
    __syncthreads();
    mx = fmaxf(fmaxf(red[0], red[1]), fmaxf(red[2], red[3]));
    float e0 = __expf(lg[0]-mx), e1 = __expf(lg[1]-mx);
    float sm = e0 + e1;
    #pragma unroll
    for (int d = 32; d > 0; d >>= 1) sm += __shfl_xor(sm, d);
    if (lane == 0) red[4+wave] = sm;
    __syncthreads();
    float inv = 1.f / (red[4]+red[5]+red[6]+red[7]);
    float a0 = e0*inv, a1 = e1*inv;
    att[tid] = a0; att[tid+256] = a1;
    bias[((size_t)h*NRES + i)*NRES + tid]       = a0;
    bias[((size_t)h*NRES + i)*NRES + tid + 256] = a1;
    __syncthreads();

    // v_out (g 0..3 -> cat[0:192]) and o_pt (g 4..9 -> LDS for transform)
    for (int g = wave; g < 10; g += 4) {
        const float4* row = (g < 4) ? &v_t4[((size_t)h*4 + g)*NRES]
                                    : &wv_t4[((size_t)h*6 + (g-4))*NRES];
        float px = 0.f, py = 0.f, pz = 0.f, pw = 0.f;
        #pragma unroll
        for (int jj = 0; jj < 8; ++jj) {
            int j = lane + jj*64;
            float a = att[j];
            float4 r = row[j];
            px += a*r.x; py += a*r.y; pz += a*r.z; pw += a*r.w;
        }
        #pragma unroll
        for (int d = 32; d > 0; d >>= 1) {
            px += __shfl_down(px, d);
            py += __shfl_down(py, d);
            pz += __shfl_down(pz, d);
            pw += __shfl_down(pw, d);
        }
        if (lane == 0) {
            if (g < 4) {
                *reinterpret_cast<float4*>(&cat[(size_t)i*CATF + h*16 + g*4]) =
                    make_float4(px, py, pz, pw);
            } else {
                int e = (g-4)*4;
                optl[e] = px; optl[e+1] = py; optl[e+2] = pz; optl[e+3] = pw;
            }
        }
    }
    __syncthreads();

    // R^T transform of o_pt + norm -> cat[192:576]
    if (tid < 8) {
        int p = tid;
        float t0 = T[i*16 + 0*4 + 3], t1 = T[i*16 + 1*4 + 3], t2 = T[i*16 + 2*4 + 3];
        float y0 = optl[p*3+0] - t0, y1 = optl[p*3+1] - t1, y2 = optl[p*3+2] - t2;
        float n2 = 0.f;
        #pragma unroll
        for (int x = 0; x < 3; ++x) {
            float w = T[i*16 + 0*4 + x]*y0 + T[i*16 + 1*4 + x]*y1 + T[i*16 + 2*4 + x]*y2;
            cat[(size_t)i*CATF + 192 + x*96 + h*8 + p] = w;
            n2 += w*w;
        }
        cat[(size_t)i*CATF + 480 + h*8 + p] = sqrtf(n2);
    }
}

// ---------------- Kernel 4: pairwise_out = att @ z  -> cat[576:2112] ----------------
__global__ __launch_bounds__(256) void k_pair(
    const float* __restrict__ z, const float* __restrict__ att,
    float* __restrict__ cat)
{
    int i = blockIdx.x, tid = threadIdx.x;
    __shared__ float zl[64*129];
    __shared__ float al[12*64];
    int c = tid & 127, hh = tid >> 7;
    float acc[6] = {0,0,0,0,0,0};
    for (int j0 = 0; j0 < NRES; j0 += 64) {
        __syncthreads();
        for (int idx = tid; idx < 64*128; idx += 256) {
            int j = idx >> 7, cc = idx & 127;
            zl[j*129 + cc] = z[((size_t)i*NRES + j0 + j)*CZ + cc];
        }
        for (int idx = tid; idx < 12*64; idx += 256) {
            int h2 = idx >> 6, jj = idx & 63;
            al[h2*64 + jj] = att[((size_t)h2*NRES + i)*NRES + j0 + jj];
        }
        __syncthreads();
        for (int jj = 0; jj < 64; ++jj) {
            float zv = zl[jj*129 + c];
            #pragma unroll
            for (int m = 0; m < 6; ++m) {
                acc[m] += al[(hh + 2*m)*64 + jj] * zv;
            }
        }
    }
    #pragma unroll
    for (int m = 0; m < 6; ++m) {
        cat[(size_t)i*CATF + 576 + (hh + 2*m)*128 + c] = acc[m];
    }
}

// ---------------- Kernel 5a: split-K Wo GEMM ----------------
// grid (64 i-blocks, 8 f-splits); part[(fs*512 + i)*384 + o]
__global__ __launch_bounds__(384) void k_wo(
    const float* __restrict__ cat, const float* __restrict__ Wo,
    float* __restrict__ part)
{
    int i0 = blockIdx.x * 8;
    int fs = blockIdx.y;
    int f0 = fs * FCHUNK;
    int tid = threadIdx.x;
    __shared__ float cl[8][FCHUNK];
    for (int idx = tid; idx < 8*(FCHUNK/4); idx += 384) {
        int j = idx / (FCHUNK/4), q = idx % (FCHUNK/4);
        *reinterpret_cast<float4*>(&cl[j][q*4]) =
            *reinterpret_cast<const float4*>(&cat[(size_t)(i0+j)*CATF + f0 + q*4]);
    }
    __syncthreads();
    float acc[8] = {0,0,0,0,0,0,0,0};
    const float* wp = Wo + (size_t)f0*CS + tid;
    #pragma unroll 4
    for (int f = 0; f < FCHUNK; ++f) {
        float w = wp[(size_t)f*CS];
        #pragma unroll
        for (int j = 0; j < 8; ++j) acc[j] = fmaf(w, cl[j][f], acc[j]);
    }
    #pragma unroll
    for (int j = 0; j < 8; ++j)
        part[((size_t)fs*NRES + i0 + j)*CS + tid] = acc[j];
}

// ---------------- Kernel 5b: reduce partials + bias ----------------
__global__ __launch_bounds__(384) void k_red(
    const float* __restrict__ part, const float* __restrict__ bo,
    float* __restrict__ out)
{
    int i = blockIdx.x, o = threadIdx.x;
    float a = bo[o];
    #pragma unroll
    for (int s = 0; s < FSPLIT; ++s)
        a += part[((size_t)s*NRES + i)*CS + o];
    out[(size_t)i*CS + o] = a;
}

// ---------------- launch ----------------
extern "C" void kernel_launch(void* const* d_in, const int* in_sizes, int n_in,
                              void* d_out, int out_size, void* d_ws, size_t ws_size,
                              hipStream_t stream)
{
    const float* s   = (const float*)d_in[0];
    const float* z   = (const float*)d_in[1];
    const float* T   = (const float*)d_in[2];
    const float* Wq  = (const float*)d_in[3];  const float* bq  = (const float*)d_in[4];
    const float* Wk  = (const float*)d_in[5];  const float* bk  = (const float*)d_in[6];
    const float* Wv  = (const float*)d_in[7];  const float* bv  = (const float*)d_in[8];
    const float* Wqp = (const float*)d_in[9];  const float* bqp = (const float*)d_in[10];
    const float* Wkp = (const float*)d_in[11]; const float* bkp = (const float*)d_in[12];
    const float* Wvp = (const float*)d_in[13]; const float* bvp = (const float*)d_in[14];
    const float* Wb  = (const float*)d_in[15]; const float* bb  = (const float*)d_in[16];
    const float* Wo  = (const float*)d_in[17]; const float* bo  = (const float*)d_in[18];
    const float* hw  = (const float*)d_in[19];
    float* out = (float*)d_out;
    float* ws  = (float*)d_ws;

    size_t off = 0;
    float* q_s  = ws + off; off += (size_t)NH*NRES*CC;
    float* k_t  = ws + off; off += (size_t)NH*NRES*CC;
    float* v_t  = ws + off; off += (size_t)NH*NRES*CC;
    float* wq   = ws + off; off += (size_t)NH*NRES*12;
    float* wk_t = ws + off; off += (size_t)NH*NRES*12;
    float* wv_t = ws + off; off += (size_t)NH*NRES*24;
    float* qn   = ws + off; off += (size_t)NH*NRES;
    float* kn   = ws + off; off += (size_t)NH*NRES;
    float* bias = ws + off; off += (size_t)NH*NRES*NRES;
    float* cat  = ws + off; off += (size_t)NRES*CATF;
    float* part = ws + off; off += (size_t)FSPLIT*NRES*CS;
    float* praw = ws + off; off += (size_t)NRES*FTOT;

    k_gemm<<<dim3(NRES/8, 3), dim3(384), 0, stream>>>(
        s, Wq, bq, Wk, bk, Wv, bv, Wqp, bqp, Wkp, bkp, Wvp, bvp, praw);

    k_post<<<dim3(NRES), dim3(256), 0, stream>>>(
        praw, T, q_s, (float4*)k_t, (float4*)v_t, wq, (float4*)wk_t, (float4*)wv_t, qn, kn);

    k_bias<<<dim3(16, NRES), dim3(384), 0, stream>>>(z, Wb, bb, bias);

    k_att<<<dim3(NRES, NH), dim3(256), 0, stream>>>(
        q_s, (const float4*)k_t, wq, (const float4*)wk_t, qn, kn, hw, T, bias,
        (const float4*)v_t, (const float4*)wv_t, cat);

    k_pair<<<dim3(NRES), dim3(256), 0, stream>>>(z, bias, cat);

    k_wo<<<dim3(NRES/8, FSPLIT), dim3(384), 0, stream>>>(cat, Wo, part);

    k_red<<<dim3(NRES), dim3(384), 0, stream>>>(part, bo, out);
}